// Round 3
// baseline (114.885 us; speedup 1.0000x reference)
//
#include <hip/hip_runtime.h>
#include <stdint.h>

// Problem constants
#define NB   32768
#define SS   11
#define DD   128
#define HH   32
#define ROWS (NB * SS)       // 360448
#define RPB  128             // rows per block in g_kernel
#define NBLK (ROWS / RPB)    // 2816
#define TPB  512             // threads per block (8 waves)
#define XSTR 136             // bf16 elems per LDS x-row (128 + 8 pad)

__device__ __forceinline__ unsigned short f2bf(float f) {
    unsigned u = __float_as_uint(f);
    unsigned r = u + 0x7fffu + ((u >> 16) & 1u);   // RNE
    return (unsigned short)(r >> 16);
}

// g[r,o] = relu(x_r @ W1 + b1) @ (Wv@Wo)[o] + (pos[r%11] @ Wv@Wo)[o]
// Verified round-1 math; 512-thread blocks for 24 waves/CU (LDS 51.7KB -> 3 blk/CU).
__global__ __launch_bounds__(TPB) void g_kernel(
    const float* __restrict__ x, const float* __restrict__ W1,
    const float* __restrict__ b1, const float* __restrict__ Wv,
    const float* __restrict__ pos, const float* __restrict__ Wo,
    float* __restrict__ g, float4* __restrict__ attn /* nullptr in fallback */)
{
    __shared__ unsigned short x_bf[RPB * XSTR];   // 34816 B
    __shared__ float w1_lds[DD * HH];             // 16384 B
    __shared__ float b1_lds[HH];
    __shared__ float M_lds[HH * 2];
    __shared__ float posM_lds[SS * 2];

    const int t   = threadIdx.x;
    const int blk = blockIdx.x;

    // ---- stage x chunk (128 rows x 128 f32) as bf16 into padded LDS ----
    const float4* xsrc = (const float4*)(x + (size_t)blk * (RPB * DD));
    #pragma unroll
    for (int k = 0; k < 8; ++k) {
        int i = t + k * TPB;           // [0, 4096)
        float4 v = xsrc[i];
        int row = i >> 5;              // 32 float4 per row
        int d4  = i & 31;
        ushort4 bv;
        bv.x = f2bf(v.x); bv.y = f2bf(v.y); bv.z = f2bf(v.z); bv.w = f2bf(v.w);
        *(ushort4*)&x_bf[row * XSTR + d4 * 4] = bv;
    }

    // ---- attn_w == 1.0 fill, overlapped with x-load latency ----
    // NBLK*TPB = 1,441,792 threads >= 991,232 float4 elements: one cond. write
    if (attn) {
        int i = blk * TPB + t;
        if (i < ROWS * SS / 4) attn[i] = make_float4(1.f, 1.f, 1.f, 1.f);
    }

    // ---- stage W1 (f32, row-major [d][j]) + b1 ----
    #pragma unroll
    for (int k = 0; k < 2; ++k)
        ((float4*)w1_lds)[t + k * TPB] = ((const float4*)W1)[t + k * TPB];
    if (t < HH) b1_lds[t] = b1[t];

    // ---- M = Wv @ Wo (32x2) ----
    if (t < 64) {
        int j = t >> 1, o = t & 1;
        float s = 0.f;
        #pragma unroll 8
        for (int k = 0; k < HH; ++k) s += Wv[j * HH + k] * Wo[k * 2 + o];
        M_lds[j * 2 + o] = s;
    }
    // ---- posM = pos_enc @ Wv @ Wo (11x2), independent recompute ----
    if (t >= 64 && t < 64 + 22) {
        int i2 = t - 64, sp = i2 >> 1, o = i2 & 1;
        float acc = 0.f;
        for (int j = 0; j < HH; ++j) {
            float m = 0.f;
            #pragma unroll 8
            for (int k = 0; k < HH; ++k) m += Wv[j * HH + k] * Wo[k * 2 + o];
            acc += pos[sp * HH + j] * m;
        }
        posM_lds[i2] = acc;
    }
    __syncthreads();

    // ---- compute: thread (rg,cg): rows rg+64p (p<2), cols cg*4..+3 ----
    // w-reads broadcast across the 8 rg-lanes sharing cg (conflict-free);
    // x-reads broadcast across the 8 cg-lanes sharing rg (conflict-free).
    const int rg = t >> 3, cg = t & 7, j0 = cg * 4;
    float acc[2][4] = {};
    #pragma unroll 4
    for (int d4 = 0; d4 < 32; ++d4) {
        float w[4][4];
        #pragma unroll
        for (int dd = 0; dd < 4; ++dd)
            *(float4*)w[dd] = *(const float4*)&w1_lds[(d4 * 4 + dd) * HH + j0];
        #pragma unroll
        for (int p = 0; p < 2; ++p) {
            uint2 xb = *(const uint2*)&x_bf[(rg + 64 * p) * XSTR + d4 * 4];
            float x0 = __uint_as_float(xb.x << 16);
            float x1 = __uint_as_float(xb.x & 0xffff0000u);
            float x2 = __uint_as_float(xb.y << 16);
            float x3 = __uint_as_float(xb.y & 0xffff0000u);
            #pragma unroll
            for (int c = 0; c < 4; ++c) {
                acc[p][c] = fmaf(x0, w[0][c],
                            fmaf(x1, w[1][c],
                            fmaf(x2, w[2][c],
                            fmaf(x3, w[3][c], acc[p][c]))));
            }
        }
    }

    // ---- relu + @M, reduce partial g over the 8 cg lanes ----
    float pg[2][2];
    #pragma unroll
    for (int p = 0; p < 2; ++p) {
        float s0 = 0.f, s1 = 0.f;
        #pragma unroll
        for (int c = 0; c < 4; ++c) {
            float y = fmaxf(acc[p][c] + b1_lds[j0 + c], 0.f);
            s0 += y * M_lds[(j0 + c) * 2 + 0];
            s1 += y * M_lds[(j0 + c) * 2 + 1];
        }
        pg[p][0] = s0; pg[p][1] = s1;
    }
    #pragma unroll
    for (int off = 1; off < 8; off <<= 1) {
        #pragma unroll
        for (int p = 0; p < 2; ++p) {
            pg[p][0] += __shfl_xor(pg[p][0], off);
            pg[p][1] += __shfl_xor(pg[p][1], off);
        }
    }
    if (cg < 2) {
        #pragma unroll
        for (int p = 0; p < 2; ++p) {
            int row = blk * RPB + rg + 64 * p;
            int sp  = row % SS;
            g[row * 2 + cg] = pg[p][cg] + posM_lds[sp * 2 + cg];
        }
    }
}

// out1[b,t,o] = bo[o] + sum_{u in [t-5,t+5] clipped to [0,10]} g[b,u,o]
__global__ __launch_bounds__(256) void out_kernel(
    const float* __restrict__ g, const float* __restrict__ bo,
    float* __restrict__ out1)
{
    int idx = blockIdx.x * 256 + threadIdx.x;       // (b,t)
    int b = idx / SS, tt = idx - b * SS;
    const float2* gb = (const float2*)(g + (size_t)b * (2 * SS));
    int lo = tt - 5 < 0 ? 0 : tt - 5;
    int hi = tt + 5 > SS - 1 ? SS - 1 : tt + 5;
    float s0 = bo[0], s1 = bo[1];
    for (int u = lo; u <= hi; ++u) { float2 v = gb[u]; s0 += v.x; s1 += v.y; }
    ((float2*)out1)[idx] = make_float2(s0, s1);
}

// fallback-only (when g must live in the attn region)
__global__ __launch_bounds__(256) void ones_kernel(float4* __restrict__ p)
{
    int i = blockIdx.x * 256 + threadIdx.x;
    p[i] = make_float4(1.f, 1.f, 1.f, 1.f);
}

extern "C" void kernel_launch(void* const* d_in, const int* in_sizes, int n_in,
                              void* d_out, int out_size, void* d_ws, size_t ws_size,
                              hipStream_t stream)
{
    const float* x   = (const float*)d_in[0];
    const float* W1  = (const float*)d_in[1];
    const float* b1  = (const float*)d_in[2];
    // d_in[3] = Wq, d_in[4] = Wk: dead (softmax over singleton dim -> attn_w == 1)
    const float* Wv  = (const float*)d_in[5];
    const float* pos = (const float*)d_in[6];
    const float* Wo  = (const float*)d_in[7];
    const float* bo  = (const float*)d_in[8];

    float* out1 = (float*)d_out;                 // (B,S,2)
    float* attn = out1 + (size_t)ROWS * 2;       // (B,S,1,11)

    const bool ws_ok = ws_size >= (size_t)ROWS * 2 * sizeof(float);
    float* g = ws_ok ? (float*)d_ws : attn;      // fallback: reuse attn region

    g_kernel<<<NBLK, TPB, 0, stream>>>(x, W1, b1, Wv, pos, Wo, g,
                                       ws_ok ? (float4*)attn : nullptr);
    out_kernel<<<ROWS / 256, 256, 0, stream>>>(g, bo, out1);
    if (!ws_ok)
        ones_kernel<<<(ROWS * SS) / 4 / 256, 256, 0, stream>>>((float4*)attn);
}

// Round 4
// 110.766 us; speedup vs baseline: 1.0372x; 1.0372x over previous
//
#include <hip/hip_runtime.h>
#include <stdint.h>

// Problem constants
#define NB   32768
#define SS   11
#define DD   128
#define HH   32
#define ROWS (NB * SS)       // 360448
#define RPB  128             // rows per block in g_kernel
#define NBLK (ROWS / RPB)    // 2816
#define TPB  256             // threads per block (4 waves)
#define XSTRD 68             // dwords per LDS x row (64 data + 4 pad) -> bank 4*rg
#define TOT4 (ROWS * SS / 4) // 991232 float4 of attn ones

__device__ __forceinline__ uint32_t f2bf_u(float f) {
    uint32_t u = __float_as_uint(f);
    return (u + 0x7fffu + ((u >> 16) & 1u)) >> 16;   // RNE
}
__device__ __forceinline__ uint32_t pkbf(float lo, float hi) {
    return f2bf_u(lo) | (f2bf_u(hi) << 16);
}
// D = a.bf16[0]*b.bf16[0] + a.bf16[1]*b.bf16[1] + c  (one VALU op, no unpack)
__device__ __forceinline__ float dot2bf(uint32_t a, uint32_t b, float c) {
    float d;
    asm("v_dot2_f32_bf16 %0, %1, %2, %3" : "=v"(d) : "v"(a), "v"(b), "v"(c));
    return d;
}

// g[r,o] = relu(x_r @ W1 + b1) @ (Wv@Wo)[o] + (pos[r%11] @ Wv@Wo)[o]
__global__ __launch_bounds__(TPB) void g_kernel(
    const float* __restrict__ x, const float* __restrict__ W1,
    const float* __restrict__ b1, const float* __restrict__ Wv,
    const float* __restrict__ pos, const float* __restrict__ Wo,
    float* __restrict__ g, float4* __restrict__ attn /* nullptr in fallback */)
{
    __shared__ uint32_t x_p[RPB * XSTRD];   // 34816 B  (bf16-pair packed x)
    __shared__ uint32_t w_p[64 * HH];       //  8192 B  (w_p[p][j] = {W1[2p][j],W1[2p+1][j]})
    __shared__ float b1_lds[HH];
    __shared__ float M_lds[HH * 2];
    __shared__ float posM_lds[SS * 2];

    const int t   = threadIdx.x;
    const int blk = blockIdx.x;

    // ---- stage x chunk (128 rows x 128 f32) as packed bf16 pairs ----
    const float4* xsrc = (const float4*)(x + (size_t)blk * (RPB * DD));
    #pragma unroll
    for (int k = 0; k < 16; ++k) {
        int i = t + k * TPB;               // [0, 4096)
        float4 v = xsrc[i];
        int row = i >> 5, d4 = i & 31;     // 32 float4 per row
        x_p[row * XSTRD + d4 * 2]     = pkbf(v.x, v.y);
        x_p[row * XSTRD + d4 * 2 + 1] = pkbf(v.z, v.w);
    }

    // ---- stage W1 as packed bf16 d-pairs: w_p[p*32+j] ----
    #pragma unroll
    for (int k = 0; k < 8; ++k) {
        int i = t + k * TPB;               // [0, 2048)
        int p = i >> 5, j = i & 31;
        w_p[i] = pkbf(W1[(2 * p) * HH + j], W1[(2 * p + 1) * HH + j]);
    }
    if (t < HH) b1_lds[t] = b1[t];

    // ---- M = Wv @ Wo (32x2) ----
    if (t >= 128 && t < 192) {
        int i2 = t - 128, j = i2 >> 1, o = i2 & 1;
        float s = 0.f;
        #pragma unroll 8
        for (int k = 0; k < HH; ++k) s += Wv[j * HH + k] * Wo[k * 2 + o];
        M_lds[i2] = s;
    }
    // ---- posM = pos_enc @ Wv @ Wo (11x2), independent recompute ----
    if (t >= 192 && t < 192 + 22) {
        int i2 = t - 192, sp = i2 >> 1, o = i2 & 1;
        float a = 0.f;
        for (int j = 0; j < HH; ++j) {
            float m = 0.f;
            #pragma unroll 8
            for (int k = 0; k < HH; ++k) m += Wv[j * HH + k] * Wo[k * 2 + o];
            a += pos[sp * HH + j] * m;
        }
        posM_lds[i2] = a;
    }

    // ---- attn_w == 1.0 fill (2816*256 = 720896 threads, 991232 float4) ----
    if (attn) {
        int i = blk * TPB + t;             // always < TOT4
        attn[i] = make_float4(1.f, 1.f, 1.f, 1.f);
        int i2 = i + NBLK * TPB;
        if (i2 < TOT4) attn[i2] = make_float4(1.f, 1.f, 1.f, 1.f);
    }
    __syncthreads();

    // ---- compute: lane=(rg_l,cg); rows rg+32rr (rr<4), cols cg*4..+3 ----
    // x-read banks: 4*rg_l + 4*p4 (8 rows x 4 banks, disjoint)  -> conflict-free
    // w-read banks: cg*16B contiguous 128B                       -> conflict-free
    const int lane = t & 63, wave = t >> 6;
    const int rgl = lane >> 3, cg = lane & 7;
    const int rg = wave * 8 + rgl, j0 = cg * 4;

    float acc[4][4] = {};
    #pragma unroll
    for (int p4 = 0; p4 < 16; ++p4) {      // 4 d-pairs (8 d) per iter
        uint32_t xv[4][4], wv[4][4];
        #pragma unroll
        for (int rr = 0; rr < 4; ++rr)
            *(uint4*)xv[rr] = *(const uint4*)&x_p[(rg + 32 * rr) * XSTRD + p4 * 4];
        #pragma unroll
        for (int pp = 0; pp < 4; ++pp)
            *(uint4*)wv[pp] = *(const uint4*)&w_p[(p4 * 4 + pp) * HH + j0];
        #pragma unroll
        for (int rr = 0; rr < 4; ++rr)
            #pragma unroll
            for (int pp = 0; pp < 4; ++pp)
                #pragma unroll
                for (int c = 0; c < 4; ++c)
                    acc[rr][c] = dot2bf(xv[rr][pp], wv[pp][c], acc[rr][c]);
    }

    // ---- relu(+b1) -> @M -> reduce over the 8 cg lanes -> +posM ----
    #pragma unroll
    for (int rr = 0; rr < 4; ++rr) {
        float s0 = 0.f, s1 = 0.f;
        #pragma unroll
        for (int c = 0; c < 4; ++c) {
            float y = fmaxf(acc[rr][c] + b1_lds[j0 + c], 0.f);
            s0 += y * M_lds[(j0 + c) * 2 + 0];
            s1 += y * M_lds[(j0 + c) * 2 + 1];
        }
        s0 += __shfl_xor(s0, 1); s1 += __shfl_xor(s1, 1);
        s0 += __shfl_xor(s0, 2); s1 += __shfl_xor(s1, 2);
        s0 += __shfl_xor(s0, 4); s1 += __shfl_xor(s1, 4);
        if (cg < 2) {
            int row = blk * RPB + rg + 32 * rr;
            int sp  = row % SS;
            g[row * 2 + cg] = (cg ? s1 : s0) + posM_lds[sp * 2 + cg];
        }
    }
}

// out1[b,t,o] = bo[o] + sum_{u in [t-5,t+5] clipped to [0,10]} g[b,u,o]
__global__ __launch_bounds__(256) void out_kernel(
    const float* __restrict__ g, const float* __restrict__ bo,
    float* __restrict__ out1)
{
    int idx = blockIdx.x * 256 + threadIdx.x;       // (b,t)
    int b = idx / SS, tt = idx - b * SS;
    const float2* gb = (const float2*)(g + (size_t)b * (2 * SS));
    int lo = tt - 5 < 0 ? 0 : tt - 5;
    int hi = tt + 5 > SS - 1 ? SS - 1 : tt + 5;
    float s0 = bo[0], s1 = bo[1];
    for (int u = lo; u <= hi; ++u) { float2 v = gb[u]; s0 += v.x; s1 += v.y; }
    ((float2*)out1)[idx] = make_float2(s0, s1);
}

// fallback-only (when g must live in the attn region)
__global__ __launch_bounds__(256) void ones_kernel(float4* __restrict__ p)
{
    int i = blockIdx.x * 256 + threadIdx.x;
    p[i] = make_float4(1.f, 1.f, 1.f, 1.f);
}

extern "C" void kernel_launch(void* const* d_in, const int* in_sizes, int n_in,
                              void* d_out, int out_size, void* d_ws, size_t ws_size,
                              hipStream_t stream)
{
    const float* x   = (const float*)d_in[0];
    const float* W1  = (const float*)d_in[1];
    const float* b1  = (const float*)d_in[2];
    // d_in[3] = Wq, d_in[4] = Wk: dead (softmax over singleton dim -> attn_w == 1)
    const float* Wv  = (const float*)d_in[5];
    const float* pos = (const float*)d_in[6];
    const float* Wo  = (const float*)d_in[7];
    const float* bo  = (const float*)d_in[8];

    float* out1 = (float*)d_out;                 // (B,S,2)
    float* attn = out1 + (size_t)ROWS * 2;       // (B,S,1,11)

    const bool ws_ok = ws_size >= (size_t)ROWS * 2 * sizeof(float);
    float* g = ws_ok ? (float*)d_ws : attn;      // fallback: reuse attn region

    g_kernel<<<NBLK, TPB, 0, stream>>>(x, W1, b1, Wv, pos, Wo, g,
                                       ws_ok ? (float4*)attn : nullptr);
    out_kernel<<<ROWS / 256, 256, 0, stream>>>(g, bo, out1);
    if (!ws_ok)
        ones_kernel<<<(ROWS * SS) / 4 / 256, 256, 0, stream>>>((float4*)attn);
}

// Round 5
// 56.615 us; speedup vs baseline: 2.0292x; 1.9565x over previous
//
#include <hip/hip_runtime.h>
#include <stdint.h>

// Problem constants
#define NB   32768
#define SS   11
#define DD   128
#define HH   32
#define ROWS (NB * SS)       // 360448
#define RPB  128             // rows per block in g_kernel
#define NBLK (ROWS / RPB)    // 2816
#define TPB  256             // threads per block (4 waves)
#define XSTRD 68             // dwords per LDS x row (64 data + 4 pad)
#define TOT4 (ROWS * SS / 4) // 991232 float4 of attn ones
#define AUXOFF (ROWS * 2)    // float offset of aux region in scratch

__device__ __forceinline__ uint32_t f2bf_u(float f) {
    uint32_t u = __float_as_uint(f);
    return (u + 0x7fffu + ((u >> 16) & 1u)) >> 16;   // RNE
}
__device__ __forceinline__ uint32_t pkbf(float lo, float hi) {
    return f2bf_u(lo) | (f2bf_u(hi) << 16);
}
// D = a.bf16[0]*b.bf16[0] + a.bf16[1]*b.bf16[1] + c  (one VALU op)
__device__ __forceinline__ float dot2bf(uint32_t a, uint32_t b, float c) {
    float d;
    asm("v_dot2_f32_bf16 %0, %1, %2, %3" : "=v"(d) : "v"(a), "v"(b), "v"(c));
    return d;
}

// One block, 64 threads. aux[0..64) = M = Wv@Wo (layout [j][o]);
// aux[64..86) = posW[t][o] = bo[o] + sum_{u in win(t)} (pos[u] @ M)[o]
__global__ __launch_bounds__(64) void setup_kernel(
    const float* __restrict__ Wv, const float* __restrict__ Wo,
    const float* __restrict__ pos, const float* __restrict__ bo,
    float* __restrict__ aux)
{
    __shared__ float M_s[HH * 2];
    __shared__ float pm_s[SS * 2];
    const int t = threadIdx.x;
    {
        int j = t >> 1, o = t & 1;
        float s = 0.f;
        #pragma unroll 8
        for (int k = 0; k < HH; ++k) s += Wv[j * HH + k] * Wo[k * 2 + o];
        M_s[t] = s;
        aux[t] = s;
    }
    __syncthreads();
    if (t < 2 * SS) {
        int u = t >> 1, o = t & 1;
        float s = 0.f;
        #pragma unroll 8
        for (int j = 0; j < HH; ++j) s += pos[u * HH + j] * M_s[j * 2 + o];
        pm_s[t] = s;
    }
    __syncthreads();
    if (t < 2 * SS) {
        int tt = t >> 1, o = t & 1;
        int lo = tt - 5 < 0 ? 0 : tt - 5;
        int hi = tt + 5 > SS - 1 ? SS - 1 : tt + 5;
        float s = bo[o];
        for (int u = lo; u <= hi; ++u) s += pm_s[u * 2 + o];
        aux[64 + t] = s;
    }
}

// g[r,o] = ( relu(x_r @ W1 + b1) @ M )[o]      (position/bias terms in posW)
__global__ __launch_bounds__(TPB) void g_kernel(
    const float* __restrict__ x, const float* __restrict__ W1,
    const float* __restrict__ b1, const float* __restrict__ aux,
    float* __restrict__ g)
{
    __shared__ uint32_t x_p[RPB * XSTRD];   // 34816 B (bf16-pair packed x)
    __shared__ uint32_t w_p[64 * HH];       //  8192 B (w_p[p][j] = {W1[2p][j],W1[2p+1][j]})

    const int t   = threadIdx.x;
    const int blk = blockIdx.x;

    // ---- stage x chunk (128 rows x 128 f32) as packed bf16 pairs ----
    const float4* xsrc = (const float4*)(x + (size_t)blk * (RPB * DD));
    #pragma unroll
    for (int k = 0; k < 16; ++k) {
        int i = t + k * TPB;               // [0, 4096)
        float4 v = xsrc[i];
        int row = i >> 5, d4 = i & 31;     // 32 float4 per row
        uint2 pv;
        pv.x = pkbf(v.x, v.y);
        pv.y = pkbf(v.z, v.w);
        *(uint2*)&x_p[row * XSTRD + d4 * 2] = pv;
    }
    // ---- stage W1 as packed bf16 d-pairs ----
    #pragma unroll
    for (int k = 0; k < 8; ++k) {
        int i = t + k * TPB;               // [0, 2048)
        int p = i >> 5, j = i & 31;
        w_p[i] = pkbf(W1[(2 * p) * HH + j], W1[(2 * p + 1) * HH + j]);
    }

    // ---- per-thread constants (global, L1-hot; independent of LDS) ----
    const int lane = t & 63, wave = t >> 6;
    const int rgl = lane >> 3, cg = lane & 7;
    const int rg = wave * 8 + rgl, j0 = cg * 4;
    const float4 b1v = *(const float4*)&b1[j0];
    const float4 mA  = *(const float4*)&aux[j0 * 2];      // M[j0][0..1], M[j0+1][0..1]
    const float4 mB  = *(const float4*)&aux[j0 * 2 + 4];  // M[j0+2][..], M[j0+3][..]
    __syncthreads();

    // ---- compute: rows rg+32rr (rr<4), cols j0..j0+3 ----
    // x-read banks: 4*(rgl+p4) mod 32, 8 disjoint quads -> conflict-free
    // w-read: broadcast across the 8 rgl lanes              -> conflict-free
    float acc[4][4] = {};
    #pragma unroll
    for (int p4 = 0; p4 < 16; ++p4) {      // 4 d-pairs (8 d) per iter
        uint32_t xv[4][4], wv[4][4];
        #pragma unroll
        for (int rr = 0; rr < 4; ++rr)
            *(uint4*)xv[rr] = *(const uint4*)&x_p[(rg + 32 * rr) * XSTRD + p4 * 4];
        #pragma unroll
        for (int pp = 0; pp < 4; ++pp)
            *(uint4*)wv[pp] = *(const uint4*)&w_p[(p4 * 4 + pp) * HH + j0];
        #pragma unroll
        for (int rr = 0; rr < 4; ++rr)
            #pragma unroll
            for (int pp = 0; pp < 4; ++pp)
                #pragma unroll
                for (int c = 0; c < 4; ++c)
                    acc[rr][c] = dot2bf(xv[rr][pp], wv[pp][c], acc[rr][c]);
    }

    // ---- relu(+b1) -> @M -> reduce over the 8 cg lanes ----
    #pragma unroll
    for (int rr = 0; rr < 4; ++rr) {
        float y0 = fmaxf(acc[rr][0] + b1v.x, 0.f);
        float y1 = fmaxf(acc[rr][1] + b1v.y, 0.f);
        float y2 = fmaxf(acc[rr][2] + b1v.z, 0.f);
        float y3 = fmaxf(acc[rr][3] + b1v.w, 0.f);
        float s0 = y0 * mA.x + y1 * mA.z + y2 * mB.x + y3 * mB.z;
        float s1 = y0 * mA.y + y1 * mA.w + y2 * mB.y + y3 * mB.w;
        s0 += __shfl_xor(s0, 1); s1 += __shfl_xor(s1, 1);
        s0 += __shfl_xor(s0, 2); s1 += __shfl_xor(s1, 2);
        s0 += __shfl_xor(s0, 4); s1 += __shfl_xor(s1, 4);
        if (cg < 2) {
            int row = blk * RPB + rg + 32 * rr;
            g[row * 2 + cg] = cg ? s1 : s0;
        }
    }
}

// out1[b,t,o] = posW[t][o] + sum_{u in [t-5,t+5] clipped} g[b,u,o]
__global__ __launch_bounds__(256) void out_kernel(
    const float* __restrict__ g, const float* __restrict__ aux,
    float* __restrict__ out1)
{
    int idx = blockIdx.x * 256 + threadIdx.x;       // (b,t)
    int b = idx / SS, tt = idx - b * SS;
    const float2* gb = (const float2*)(g + (size_t)b * (2 * SS));
    int lo = tt - 5 < 0 ? 0 : tt - 5;
    int hi = tt + 5 > SS - 1 ? SS - 1 : tt + 5;
    float2 pw = *(const float2*)&aux[64 + tt * 2];
    float s0 = pw.x, s1 = pw.y;
    for (int u = lo; u <= hi; ++u) { float2 v = gb[u]; s0 += v.x; s1 += v.y; }
    ((float2*)out1)[idx] = make_float2(s0, s1);
}

// attn_w == softmax over singleton dim == 1.0 everywhere
__global__ __launch_bounds__(256) void ones_kernel(float4* __restrict__ p)
{
    int i = blockIdx.x * 256 + threadIdx.x;
    p[i] = make_float4(1.f, 1.f, 1.f, 1.f);
}

extern "C" void kernel_launch(void* const* d_in, const int* in_sizes, int n_in,
                              void* d_out, int out_size, void* d_ws, size_t ws_size,
                              hipStream_t stream)
{
    const float* x   = (const float*)d_in[0];
    const float* W1  = (const float*)d_in[1];
    const float* b1  = (const float*)d_in[2];
    // d_in[3] = Wq, d_in[4] = Wk: dead (softmax over singleton dim -> attn_w == 1)
    const float* Wv  = (const float*)d_in[5];
    const float* pos = (const float*)d_in[6];
    const float* Wo  = (const float*)d_in[7];
    const float* bo  = (const float*)d_in[8];

    float* out1 = (float*)d_out;                 // (B,S,2)
    float* attn = out1 + (size_t)ROWS * 2;       // (B,S,1,11)

    const bool ws_ok = ws_size >= (size_t)(AUXOFF + 128) * sizeof(float);
    float* base = ws_ok ? (float*)d_ws : attn;   // fallback: reuse attn region
    float* g    = base;                          // ROWS*2 floats
    float* aux  = base + AUXOFF;                 // 86 floats (M + posW)

    // order matters in fallback: aux/g consumed before ones_kernel overwrites
    setup_kernel<<<1, 64, 0, stream>>>(Wv, Wo, pos, bo, aux);
    g_kernel<<<NBLK, TPB, 0, stream>>>(x, W1, b1, aux, g);
    out_kernel<<<ROWS / 256, 256, 0, stream>>>(g, aux, out1);
    ones_kernel<<<TOT4 / 256, 256, 0, stream>>>((float4*)attn);
}

// Round 6
// 54.969 us; speedup vs baseline: 2.0900x; 1.0299x over previous
//
#include <hip/hip_runtime.h>
#include <stdint.h>

// Problem constants
#define NB   32768
#define SS   11
#define DD   128
#define HH   32
#define ROWS (NB * SS)       // 360448
#define RPB  128             // rows per block in g_kernel
#define NBLK (ROWS / RPB)    // 2816
#define TPB  256             // threads per block (4 waves)
#define XSTRD 68             // dwords per LDS x row (64 data + 4 pad)
#define TOT4 (ROWS * SS / 4) // 991232 float4 of attn ones
#define AUXOFF (ROWS * 2)    // float offset of aux region in scratch

__device__ __forceinline__ uint32_t f2bf_u(float f) {
    uint32_t u = __float_as_uint(f);
    return (u + 0x7fffu + ((u >> 16) & 1u)) >> 16;   // RNE
}
__device__ __forceinline__ uint32_t pkbf(float lo, float hi) {
    return f2bf_u(lo) | (f2bf_u(hi) << 16);
}
// D = a.bf16[0]*b.bf16[0] + a.bf16[1]*b.bf16[1] + c  (one VALU op)
__device__ __forceinline__ float dot2bf(uint32_t a, uint32_t b, float c) {
    float d;
    asm("v_dot2_f32_bf16 %0, %1, %2, %3" : "=v"(d) : "v"(a), "v"(b), "v"(c));
    return d;
}
// returns v[lane] + v[lane^32] for every lane, VALU-only (no LDS pipe).
// Any half-exchange semantic of permlane32_swap leaves {a',b'} holding one
// copy of v[i] and one of v[i^32] per lane, so a'+b' is the xor-32 sum.
__device__ __forceinline__ float xor32sum(float v) {
    float a = v, b = v;
    asm("v_permlane32_swap_b32 %0, %1" : "+v"(a), "+v"(b));
    return a + b;
}

// One block, 64 threads. aux[0..64) = M = Wv@Wo (layout [j][o]);
// aux[64..86) = posW[t][o] = bo[o] + sum_{u in win(t)} (pos[u] @ M)[o]
__global__ __launch_bounds__(64) void setup_kernel(
    const float* __restrict__ Wv, const float* __restrict__ Wo,
    const float* __restrict__ pos, const float* __restrict__ bo,
    float* __restrict__ aux)
{
    __shared__ float M_s[HH * 2];
    __shared__ float pm_s[SS * 2];
    const int t = threadIdx.x;
    {
        int j = t >> 1, o = t & 1;
        float s = 0.f;
        #pragma unroll 8
        for (int k = 0; k < HH; ++k) s += Wv[j * HH + k] * Wo[k * 2 + o];
        M_s[t] = s;
        aux[t] = s;
    }
    __syncthreads();
    if (t < 2 * SS) {
        int u = t >> 1, o = t & 1;
        float s = 0.f;
        #pragma unroll 8
        for (int j = 0; j < HH; ++j) s += pos[u * HH + j] * M_s[j * 2 + o];
        pm_s[t] = s;
    }
    __syncthreads();
    if (t < 2 * SS) {
        int tt = t >> 1, o = t & 1;
        int lo = tt - 5 < 0 ? 0 : tt - 5;
        int hi = tt + 5 > SS - 1 ? SS - 1 : tt + 5;
        float s = bo[o];
        for (int u = lo; u <= hi; ++u) s += pm_s[u * 2 + o];
        aux[64 + t] = s;
    }
}

// g[r,o] = ( relu(x_r @ W1 + b1) @ M )[o]      (pos/bias terms live in posW)
// Lane split: cg=lane&3 (8 cols), rg=(lane>>2)&7 (4 rows, stride 8),
// kc=lane>>5 (K halved). kc-reduce via permlane32_swap (VALU, not LDS pipe).
__global__ __launch_bounds__(TPB, 3) void g_kernel(
    const float* __restrict__ x, const float* __restrict__ W1,
    const float* __restrict__ b1, const float* __restrict__ aux,
    float* __restrict__ g)
{
    __shared__ uint32_t x_p[RPB * XSTRD];   // 34816 B (bf16-pair packed x)
    __shared__ uint32_t w_p[64 * HH];       //  8192 B (w_p[p][j] = {W1[2p][j],W1[2p+1][j]})

    const int t   = threadIdx.x;
    const int blk = blockIdx.x;

    // ---- stage x chunk (128 rows x 128 f32): 8 floats -> uint4 -> b128 write ----
    const float4* xsrc = (const float4*)(x + (size_t)blk * (RPB * DD));
    #pragma unroll
    for (int k = 0; k < 8; ++k) {
        int j = t + k * TPB;               // [0, 2048)
        float4 v0 = xsrc[2 * j], v1 = xsrc[2 * j + 1];
        uint4 pv;
        pv.x = pkbf(v0.x, v0.y); pv.y = pkbf(v0.z, v0.w);
        pv.z = pkbf(v1.x, v1.y); pv.w = pkbf(v1.z, v1.w);
        int row = j >> 4, d8 = j & 15;     // 16 uint4 per row
        *(uint4*)&x_p[row * XSTRD + d8 * 4] = pv;
    }
    // ---- stage W1 as packed bf16 d-pairs ----
    #pragma unroll
    for (int k = 0; k < 8; ++k) {
        int i = t + k * TPB;               // [0, 2048)
        int p = i >> 5, j = i & 31;
        w_p[i] = pkbf(W1[(2 * p) * HH + j], W1[(2 * p + 1) * HH + j]);
    }

    const int lane = t & 63, wave = t >> 6;
    const int cg = lane & 3;           // cols j0..j0+7
    const int rg = (lane >> 2) & 7;    // rows rbase+8rr
    const int kc = lane >> 5;          // pairs kc*32..+31
    const int j0 = cg * 8;
    const int rbase = wave * 32 + rg;

    // per-thread constants (global, L1-hot; independent of LDS)
    float b1v[8], Mv[16];
    *(float4*)&b1v[0] = *(const float4*)&b1[j0];
    *(float4*)&b1v[4] = *(const float4*)&b1[j0 + 4];
    #pragma unroll
    for (int q = 0; q < 4; ++q)
        *(float4*)&Mv[q * 4] = *(const float4*)&aux[j0 * 2 + q * 4];
    __syncthreads();

    // ---- compute: 4 rows x 8 cols x 32 pairs per thread ----
    // x-read banks: 4rg quads, kc 2-way same-bank-diff-addr (free), cg bcast
    // w-read banks: 8cg+4q distinct quads, kc 2-way (free), rg bcast
    float acc[4][8] = {};
    #pragma unroll
    for (int i = 0; i < 8; ++i) {          // 4 d-pairs per iter
        uint32_t xv[4][4], wv[4][8];
        #pragma unroll
        for (int rr = 0; rr < 4; ++rr)
            *(uint4*)xv[rr] = *(const uint4*)&x_p[(rbase + 8 * rr) * XSTRD + kc * 32 + i * 4];
        #pragma unroll
        for (int pp = 0; pp < 4; ++pp) {
            *(uint4*)&wv[pp][0] = *(const uint4*)&w_p[(kc * 32 + i * 4 + pp) * HH + j0];
            *(uint4*)&wv[pp][4] = *(const uint4*)&w_p[(kc * 32 + i * 4 + pp) * HH + j0 + 4];
        }
        #pragma unroll
        for (int rr = 0; rr < 4; ++rr)
            #pragma unroll
            for (int pp = 0; pp < 4; ++pp)
                #pragma unroll
                for (int c = 0; c < 8; ++c)
                    acc[rr][c] = dot2bf(xv[rr][pp], wv[pp][c], acc[rr][c]);
    }

    // ---- epilogue: kc-sum (VALU) -> relu(+b1) -> @M -> cg-reduce -> store ----
    #pragma unroll
    for (int rr = 0; rr < 4; ++rr) {
        float s0 = 0.f, s1 = 0.f;
        #pragma unroll
        for (int c = 0; c < 8; ++c) {
            float full = xor32sum(acc[rr][c]);         // sum over kc halves
            float y = fmaxf(full + b1v[c], 0.f);
            s0 = fmaf(y, Mv[c * 2], s0);
            s1 = fmaf(y, Mv[c * 2 + 1], s1);
        }
        s0 += __shfl_xor(s0, 1); s1 += __shfl_xor(s1, 1);
        s0 += __shfl_xor(s0, 2); s1 += __shfl_xor(s1, 2);
        if ((lane & 35) == 0) {            // cg==0 && kc==0
            int row = blk * RPB + rbase + 8 * rr;
            ((float2*)g)[row] = make_float2(s0, s1);
        }
    }
}

// merged: attn ones fill + out1 window sum (ws_ok path only)
__global__ __launch_bounds__(256) void outones_kernel(
    const float* __restrict__ g, const float* __restrict__ aux,
    float* __restrict__ out1, float4* __restrict__ attn)
{
    int idx = blockIdx.x * 256 + threadIdx.x;       // [0, TOT4)
    attn[idx] = make_float4(1.f, 1.f, 1.f, 1.f);
    if (idx < ROWS) {
        int b = idx / SS, tt = idx - b * SS;
        const float2* gb = (const float2*)(g + (size_t)b * (2 * SS));
        int lo = tt - 5 < 0 ? 0 : tt - 5;
        int hi = tt + 5 > SS - 1 ? SS - 1 : tt + 5;
        float2 pw = *(const float2*)&aux[64 + tt * 2];
        float s0 = pw.x, s1 = pw.y;
        for (int u = lo; u <= hi; ++u) { float2 v = gb[u]; s0 += v.x; s1 += v.y; }
        ((float2*)out1)[idx] = make_float2(s0, s1);
    }
}

// fallback-only pair (g aliased into attn region: must read g before ones)
__global__ __launch_bounds__(256) void out_kernel(
    const float* __restrict__ g, const float* __restrict__ aux,
    float* __restrict__ out1)
{
    int idx = blockIdx.x * 256 + threadIdx.x;
    int b = idx / SS, tt = idx - b * SS;
    const float2* gb = (const float2*)(g + (size_t)b * (2 * SS));
    int lo = tt - 5 < 0 ? 0 : tt - 5;
    int hi = tt + 5 > SS - 1 ? SS - 1 : tt + 5;
    float2 pw = *(const float2*)&aux[64 + tt * 2];
    float s0 = pw.x, s1 = pw.y;
    for (int u = lo; u <= hi; ++u) { float2 v = gb[u]; s0 += v.x; s1 += v.y; }
    ((float2*)out1)[idx] = make_float2(s0, s1);
}
__global__ __launch_bounds__(256) void ones_kernel(float4* __restrict__ p)
{
    int i = blockIdx.x * 256 + threadIdx.x;
    p[i] = make_float4(1.f, 1.f, 1.f, 1.f);
}

extern "C" void kernel_launch(void* const* d_in, const int* in_sizes, int n_in,
                              void* d_out, int out_size, void* d_ws, size_t ws_size,
                              hipStream_t stream)
{
    const float* x   = (const float*)d_in[0];
    const float* W1  = (const float*)d_in[1];
    const float* b1  = (const float*)d_in[2];
    // d_in[3] = Wq, d_in[4] = Wk: dead (softmax over singleton dim -> attn_w == 1)
    const float* Wv  = (const float*)d_in[5];
    const float* pos = (const float*)d_in[6];
    const float* Wo  = (const float*)d_in[7];
    const float* bo  = (const float*)d_in[8];

    float* out1 = (float*)d_out;                 // (B,S,2)
    float* attn = out1 + (size_t)ROWS * 2;       // (B,S,1,11)

    const bool ws_ok = ws_size >= (size_t)(AUXOFF + 128) * sizeof(float);
    float* base = ws_ok ? (float*)d_ws : attn;   // fallback: reuse attn region
    float* g    = base;                          // ROWS*2 floats
    float* aux  = base + AUXOFF;                 // 86 floats (M + posW)

    setup_kernel<<<1, 64, 0, stream>>>(Wv, Wo, pos, bo, aux);
    g_kernel<<<NBLK, TPB, 0, stream>>>(x, W1, b1, aux, g);
    if (ws_ok) {
        outones_kernel<<<TOT4 / 256, 256, 0, stream>>>(g, aux, out1, (float4*)attn);
    } else {
        out_kernel<<<ROWS / 256, 256, 0, stream>>>(g, aux, out1);
        ones_kernel<<<TOT4 / 256, 256, 0, stream>>>((float4*)attn);
    }
}